// Round 4
// baseline (85.119 us; speedup 1.0000x reference)
//
#include <hip/hip_runtime.h>
#include <math.h>

// Problem geometry (fixed): B=4, N=16, K=16, H=64, O=1
// W: (a,b,d,e,k,o) = 16^4 x 16 x 64 fp32 = 256 MiB -> memory-bound on W.
//
// h[z,a,o] = sum_{j=(b,d,e,k)} P[z,a,j] * W[a,j,o]
// P[z,a,j] = sum_c basis[z,a,b,k,c] * basis[z,d,e,k,c]
// out[z,a] = silu(h[z,a,:]) . w_fc + b_fc
//
// ws layout (floats):
//   basisv : [1024 pairs][16 k] float4 (xyz,pad) =    65,536 floats @ 0
//   P      : f32x4[16][65536] (over z)           = 4,194,304 floats @ 65,536
//   part   : [16][128][256]                      =   524,288 floats @ 4,259,840
//   total 4,784,128 floats = 19.1 MB

#define NAT 16
#define NKR 16
#define NHID 64
#define NJ 65536
#define BPA 128  // blocks per 'a' in k_main -> 2048 blocks = 8 blocks/CU

typedef float f32x4 __attribute__((ext_vector_type(4)));

static constexpr double D_START = 0.006737946999085467; // exp(-5)

__global__ void k_basis(const float* __restrict__ x, f32x4* __restrict__ basisv) {
    int t = blockIdx.x * blockDim.x + threadIdx.x; // (z,p,q): 4*16*16 = 1024
    if (t >= 4 * NAT * NAT) return;
    int q = t & 15, p = (t >> 4) & 15, z = t >> 8;
    const float* xp = x + (z * NAT + p) * 3;
    const float* xq = x + (z * NAT + q) * 3;
    float d0 = xp[0] - xq[0], d1 = xp[1] - xq[1], d2 = xp[2] - xq[2];
    float nsq = d0 * d0 + d1 * d1 + d2 * d2 + 1e-5f;
    float nrm = sqrtf(nsq);
    // faithful to reference: diff /= norm^2
    float b0 = d0 / nsq, b1 = d1 / nsq, b2 = d2 / nsq;
    float cut = (nrm < 5.0f) ? 0.5f * (cosf(nrm * 0.6283185307179586f) + 1.0f) : 0.0f;
    float ex = expf(-nrm); // alpha=1, CUT_LO=0
    const float START = (float)D_START;
    const float STEP  = (float)((1.0 - D_START) / 15.0);
    const float BETA  = (float)(1.0 / ((0.125 * (1.0 - D_START)) * (0.125 * (1.0 - D_START))));
    f32x4* o = basisv + (size_t)t * NKR;
    #pragma unroll
    for (int k = 0; k < NKR; ++k) {
        float m = START + STEP * (float)k;
        float dmm = ex - m;
        float s = cut * expf(-BETA * dmm * dmm);
        f32x4 v; v.x = s * b0; v.y = s * b1; v.z = s * b2; v.w = 0.f;
        o[k] = v;
    }
}

// Each thread computes P for 4 consecutive j (same b,d,e; k = kq*4..kq*4+3), all 4 z.
__global__ __launch_bounds__(256) void k_pmat(const f32x4* __restrict__ basisv,
                                              f32x4* __restrict__ P) {
    int tt = blockIdx.x * 256 + threadIdx.x;      // 262,144 total
    int kq = tt & 3;
    int e  = (tt >> 2) & 15;
    int d  = (tt >> 6) & 15;
    int b  = (tt >> 10) & 15;
    int a  = (tt >> 14) & 15;
    int k0 = kq * 4;

    f32x4 u[4][4], v[4][4];
    #pragma unroll
    for (int z = 0; z < 4; ++z) {
        const f32x4* up = basisv + ((size_t)((z * 16 + a) * 16 + b)) * NKR + k0;
        const f32x4* vp = basisv + ((size_t)((z * 16 + d) * 16 + e)) * NKR + k0;
        #pragma unroll
        for (int kk = 0; kk < 4; ++kk) { u[z][kk] = up[kk]; v[z][kk] = vp[kk]; }
    }
    size_t jbase = (size_t)a * NJ + (((b * 16 + d) * 16 + e) * 16 + k0);
    #pragma unroll
    for (int kk = 0; kk < 4; ++kk) {
        f32x4 pv;
        #pragma unroll
        for (int z = 0; z < 4; ++z)
            pv[z] = u[z][kk].x * v[z][kk].x + u[z][kk].y * v[z][kk].y + u[z][kk].z * v[z][kk].z;
        P[jbase + kk] = pv;
    }
}

__global__ __launch_bounds__(256, 8) void k_main(const f32x4* __restrict__ W4,
                                                 const f32x4* __restrict__ P,
                                                 float* __restrict__ part) {
    int a    = blockIdx.x >> 7;       // blockIdx / BPA
    int blk  = blockIdx.x & (BPA - 1);
    int wave = threadIdx.x >> 6;
    int lane = threadIdx.x & 63;
    int og   = lane & 15;  // which group of 4 'o' columns
    int rsub = lane >> 4;  // row within the 4-row group
    int gbase = (blk * 4 + wave) * 32; // 32 row-groups per wave, contiguous

    float acc[4][4] = {{0.f, 0.f, 0.f, 0.f}, {0.f, 0.f, 0.f, 0.f},
                       {0.f, 0.f, 0.f, 0.f}, {0.f, 0.f, 0.f, 0.f}};
    size_t abase = (size_t)a * NJ;
    #pragma unroll 2
    for (int g = 0; g < 32; ++g) {
        size_t row = abase + (size_t)((gbase + g) * 4 + rsub);
        f32x4 p4 = P[row];             // 16B, broadcast within 16-lane group (L2-hot)
        f32x4 w4 = __builtin_nontemporal_load(&W4[row * 16 + og]); // streamed once
        acc[0][0] += p4.x * w4.x; acc[0][1] += p4.x * w4.y; acc[0][2] += p4.x * w4.z; acc[0][3] += p4.x * w4.w;
        acc[1][0] += p4.y * w4.x; acc[1][1] += p4.y * w4.y; acc[1][2] += p4.y * w4.z; acc[1][3] += p4.y * w4.w;
        acc[2][0] += p4.z * w4.x; acc[2][1] += p4.z * w4.y; acc[2][2] += p4.z * w4.z; acc[2][3] += p4.z * w4.w;
        acc[3][0] += p4.w * w4.x; acc[3][1] += p4.w * w4.y; acc[3][2] += p4.w * w4.z; acc[3][3] += p4.w * w4.w;
    }
    // reduce across the 4 row-subgroups (lane bits 4,5)
    #pragma unroll
    for (int z = 0; z < 4; ++z) {
        #pragma unroll
        for (int c = 0; c < 4; ++c) {
            float v = acc[z][c];
            v += __shfl_xor(v, 16);
            v += __shfl_xor(v, 32);
            acc[z][c] = v;
        }
    }
    __shared__ float red[4][256];
    if (rsub == 0) {
        #pragma unroll
        for (int z = 0; z < 4; ++z) {
            #pragma unroll
            for (int c = 0; c < 4; ++c)
                red[wave][z * 64 + og * 4 + c] = acc[z][c];
        }
    }
    __syncthreads();
    int t = threadIdx.x; // (z*64 + o)
    float s = red[0][t] + red[1][t] + red[2][t] + red[3][t];
    part[((size_t)a * BPA + blk) * 256 + t] = s;
}

__global__ void k_out(const float* __restrict__ part, const float* __restrict__ w_fc,
                      const float* __restrict__ b_fc, float* __restrict__ out) {
    // one block per (z,a); 256 threads = 4 blk-quarters x 64 'o'
    int z = blockIdx.x >> 4, a = blockIdx.x & 15;
    int o = threadIdx.x & 63, bq = threadIdx.x >> 6;
    float s = 0.f;
    for (int blk = bq; blk < BPA; blk += 4)
        s += part[((size_t)a * BPA + blk) * 256 + z * 64 + o]; // coalesced over o
    __shared__ float red[4][64];
    red[bq][o] = s;
    __syncthreads();
    if (threadIdx.x < 64) {
        float h = red[0][o] + red[1][o] + red[2][o] + red[3][o];
        float v = h * (1.0f / (1.0f + expf(-h))) * w_fc[o]; // silu * weight
        #pragma unroll
        for (int off = 32; off >= 1; off >>= 1) v += __shfl_xor(v, off);
        if (o == 0) out[z * 16 + a] = v + b_fc[0];
    }
}

extern "C" void kernel_launch(void* const* d_in, const int* in_sizes, int n_in,
                              void* d_out, int out_size, void* d_ws, size_t ws_size,
                              hipStream_t stream) {
    const float* x    = (const float*)d_in[0];
    const float* W    = (const float*)d_in[1];
    const float* w_fc = (const float*)d_in[2];
    const float* b_fc = (const float*)d_in[3];
    float* ws = (float*)d_ws;

    f32x4*  basisv = (f32x4*)ws;                           // 65,536 floats
    f32x4*  P      = (f32x4*)(ws + 65536);                 // 4,194,304 floats
    float*  part   = ws + 65536 + (size_t)NAT * NJ * 4;    // 524,288 floats
    float*  out    = (float*)d_out;

    k_basis<<<16, 64, 0, stream>>>(x, basisv);
    k_pmat<<<1024, 256, 0, stream>>>(basisv, P);
    k_main<<<NAT * BPA, 256, 0, stream>>>((const f32x4*)W, P, part);
    k_out<<<64, 256, 0, stream>>>(part, w_fc, b_fc, out);
}

// Round 5
// 64.999 us; speedup vs baseline: 1.3095x; 1.3095x over previous
//
#include <hip/hip_runtime.h>
#include <math.h>

// Problem geometry (fixed): B=4, N=16, K=16, H=64, O=1
// W: (a,b,d,e,k,o) = 16^4 x 16 x 64 fp32 = 256 MiB -> memory-bound on W.
//
// h[z,a,o] = sum_{j=(b,d,e,k)} P[z,a,j] * W[a,j,o]
// P[z,a,j] = sum_c basis[z,a,b,k,c] * basis[z,d,e,k,c]
// out[z,a] = silu(h[z,a,:]) . w_fc + b_fc
//
// P is never materialized in HBM: each k_main block covers 512 consecutive
// j-rows (1 b, 2 d, 16 e, 16 k) and computes their P values into 8 KB LDS
// from the 256 KB basis table (L2-hot).
//
// ws layout (floats):
//   basisv : [1024 pairs][16 k] float4 (xyz,pad) = 65,536 floats @ 0
//   part   : [16][128][256]                      = 524,288 floats @ 65,536
//   total 589,824 floats = 2.36 MB

#define NAT 16
#define NKR 16
#define NHID 64
#define NJ 65536
#define BPA 128  // blocks per 'a' -> 2048 blocks = 8 blocks/CU = 32 waves/CU

typedef float f32x4 __attribute__((ext_vector_type(4)));

static constexpr double D_START = 0.006737946999085467; // exp(-5)

__global__ void k_basis(const float* __restrict__ x, f32x4* __restrict__ basisv) {
    int t = blockIdx.x * blockDim.x + threadIdx.x; // (z,p,q): 4*16*16 = 1024
    if (t >= 4 * NAT * NAT) return;
    int q = t & 15, p = (t >> 4) & 15, z = t >> 8;
    const float* xp = x + (z * NAT + p) * 3;
    const float* xq = x + (z * NAT + q) * 3;
    float d0 = xp[0] - xq[0], d1 = xp[1] - xq[1], d2 = xp[2] - xq[2];
    float nsq = d0 * d0 + d1 * d1 + d2 * d2 + 1e-5f;
    float nrm = sqrtf(nsq);
    // faithful to reference: diff /= norm^2
    float b0 = d0 / nsq, b1 = d1 / nsq, b2 = d2 / nsq;
    float cut = (nrm < 5.0f) ? 0.5f * (cosf(nrm * 0.6283185307179586f) + 1.0f) : 0.0f;
    float ex = expf(-nrm); // alpha=1, CUT_LO=0
    const float START = (float)D_START;
    const float STEP  = (float)((1.0 - D_START) / 15.0);
    const float BETA  = (float)(1.0 / ((0.125 * (1.0 - D_START)) * (0.125 * (1.0 - D_START))));
    f32x4* o = basisv + (size_t)t * NKR;
    #pragma unroll
    for (int k = 0; k < NKR; ++k) {
        float m = START + STEP * (float)k;
        float dmm = ex - m;
        float s = cut * expf(-BETA * dmm * dmm);
        f32x4 v; v.x = s * b0; v.y = s * b1; v.z = s * b2; v.w = 0.f;
        o[k] = v;
    }
}

__global__ __launch_bounds__(256, 8) void k_main(const f32x4* __restrict__ W4,
                                                 const f32x4* __restrict__ basisv,
                                                 float* __restrict__ part) {
    int a   = blockIdx.x >> 7;        // blockIdx / BPA
    int blk = blockIdx.x & (BPA - 1);

    __shared__ f32x4 p_lds[512];
    __shared__ float red[4][256];

    // ---- prologue: P for this block's 512 j-rows (j = blk*512 + r) ----
    {
        int t = threadIdx.x;
        int e = (t >> 4) & 15, k = t & 15;
        int b = blk >> 3, dd = (blk & 7) * 2;
        f32x4 p0, p1;
        #pragma unroll
        for (int z = 0; z < 4; ++z) {
            f32x4 u  = basisv[(((z * 16 + a)  * 16 + b)      * 16) + k];
            f32x4 v0 = basisv[(((z * 16 + dd) * 16 + e)      * 16) + k];
            f32x4 v1 = basisv[(((z * 16 + dd + 1) * 16 + e)  * 16) + k];
            p0[z] = u.x * v0.x + u.y * v0.y + u.z * v0.z;
            p1[z] = u.x * v1.x + u.y * v1.y + u.z * v1.z;
        }
        p_lds[t]       = p0;  // r = t       (dd+0)
        p_lds[t + 256] = p1;  // r = t + 256 (dd+1)
    }
    __syncthreads();

    int wave = threadIdx.x >> 6;
    int lane = threadIdx.x & 63;
    int og   = lane & 15;  // group of 4 'o' columns
    int rsub = lane >> 4;  // row within the 4-row group

    float acc[4][4] = {{0.f, 0.f, 0.f, 0.f}, {0.f, 0.f, 0.f, 0.f},
                       {0.f, 0.f, 0.f, 0.f}, {0.f, 0.f, 0.f, 0.f}};
    size_t rowbase = (size_t)a * NJ + (size_t)blk * 512;
    #pragma unroll 2
    for (int g = 0; g < 32; ++g) {
        int rloc = wave * 128 + g * 4 + rsub;   // 0..511
        f32x4 p4 = p_lds[rloc];                 // 64 B unique per wave-iter
        f32x4 w4 = __builtin_nontemporal_load(&W4[(rowbase + rloc) * 16 + og]);
        acc[0][0] += p4.x * w4.x; acc[0][1] += p4.x * w4.y; acc[0][2] += p4.x * w4.z; acc[0][3] += p4.x * w4.w;
        acc[1][0] += p4.y * w4.x; acc[1][1] += p4.y * w4.y; acc[1][2] += p4.y * w4.z; acc[1][3] += p4.y * w4.w;
        acc[2][0] += p4.z * w4.x; acc[2][1] += p4.z * w4.y; acc[2][2] += p4.z * w4.z; acc[2][3] += p4.z * w4.w;
        acc[3][0] += p4.w * w4.x; acc[3][1] += p4.w * w4.y; acc[3][2] += p4.w * w4.z; acc[3][3] += p4.w * w4.w;
    }
    // reduce across the 4 row-subgroups (lane bits 4,5)
    #pragma unroll
    for (int z = 0; z < 4; ++z) {
        #pragma unroll
        for (int c = 0; c < 4; ++c) {
            float v = acc[z][c];
            v += __shfl_xor(v, 16);
            v += __shfl_xor(v, 32);
            acc[z][c] = v;
        }
    }
    if (rsub == 0) {
        #pragma unroll
        for (int z = 0; z < 4; ++z) {
            #pragma unroll
            for (int c = 0; c < 4; ++c)
                red[wave][z * 64 + og * 4 + c] = acc[z][c];
        }
    }
    __syncthreads();
    int t = threadIdx.x; // (z*64 + o)
    float s = red[0][t] + red[1][t] + red[2][t] + red[3][t];
    part[((size_t)a * BPA + blk) * 256 + t] = s;
}

__global__ void k_out(const float* __restrict__ part, const float* __restrict__ w_fc,
                      const float* __restrict__ b_fc, float* __restrict__ out) {
    // one block per (z,a); 256 threads = 4 blk-quarters x 64 'o'
    int z = blockIdx.x >> 4, a = blockIdx.x & 15;
    int o = threadIdx.x & 63, bq = threadIdx.x >> 6;
    float s = 0.f;
    for (int blk = bq; blk < BPA; blk += 4)
        s += part[((size_t)a * BPA + blk) * 256 + z * 64 + o]; // coalesced over o
    __shared__ float red[4][64];
    red[bq][o] = s;
    __syncthreads();
    if (threadIdx.x < 64) {
        float h = red[0][o] + red[1][o] + red[2][o] + red[3][o];
        float v = h * (1.0f / (1.0f + expf(-h))) * w_fc[o]; // silu * weight
        #pragma unroll
        for (int off = 32; off >= 1; off >>= 1) v += __shfl_xor(v, off);
        if (o == 0) out[z * 16 + a] = v + b_fc[0];
    }
}

extern "C" void kernel_launch(void* const* d_in, const int* in_sizes, int n_in,
                              void* d_out, int out_size, void* d_ws, size_t ws_size,
                              hipStream_t stream) {
    const float* x    = (const float*)d_in[0];
    const float* W    = (const float*)d_in[1];
    const float* w_fc = (const float*)d_in[2];
    const float* b_fc = (const float*)d_in[3];
    float* ws = (float*)d_ws;

    f32x4*  basisv = (f32x4*)ws;        // 65,536 floats
    float*  part   = ws + 65536;        // 524,288 floats
    float*  out    = (float*)d_out;

    k_basis<<<4, 256, 0, stream>>>(x, basisv);
    k_main<<<NAT * BPA, 256, 0, stream>>>((const f32x4*)W, basisv, part);
    k_out<<<64, 256, 0, stream>>>(part, w_fc, b_fc, out);
}

// Round 6
// 61.823 us; speedup vs baseline: 1.3768x; 1.0514x over previous
//
#include <hip/hip_runtime.h>
#include <math.h>

// Problem geometry (fixed): B=4, N=16, K=16, H=64, O=1
// W: (a,b,d,e,k,o) = 16^4 x 16 x 64 fp32 = 256 MiB -> memory-bound on W.
//
// h[z,a,o] = sum_{j=(b,d,e,k)} P[z,a,j] * W[a,j,o]
// P[z,a,j] = sum_c basis[z,a,b,k,c] * basis[z,d,e,k,c]
// out[z,a] = silu(h[z,a,:]) . w_fc + b_fc
//
// Neither basis nor P ever touch HBM: each k_main block covers 512
// consecutive j-rows (1 b, 2 d, 16 e, 16 k) and computes their P values
// straight from x (192 B, L1-hot) into 8 KB LDS in a ~500-cycle prologue.
//
// ws layout (floats): part : [16][128][256] = 524,288 floats = 2 MB

#define NJ 65536
#define BPA 128  // blocks per 'a' -> 2048 blocks

typedef float f32x4 __attribute__((ext_vector_type(4)));

static constexpr double D_START = 0.006737946999085467; // exp(-5)

// basis vector (smear_k * diff / nsq) for pair (p,q) in batch z, rbf k
__device__ __forceinline__ void pair_basis(const float* __restrict__ x,
                                           int z, int p, int q, int k,
                                           float& bx, float& by, float& bz) {
    const float* xp = x + (z * 16 + p) * 3;
    const float* xq = x + (z * 16 + q) * 3;
    float d0 = xp[0] - xq[0], d1 = xp[1] - xq[1], d2 = xp[2] - xq[2];
    float nsq = d0 * d0 + d1 * d1 + d2 * d2 + 1e-5f;
    float nrm = sqrtf(nsq);
    float cut = (nrm < 5.0f) ? 0.5f * (cosf(nrm * 0.6283185307179586f) + 1.0f) : 0.0f;
    float ex = expf(-nrm); // alpha=1, CUT_LO=0
    const float START = (float)D_START;
    const float STEP  = (float)((1.0 - D_START) / 15.0);
    const float BETA  = (float)(1.0 / ((0.125 * (1.0 - D_START)) * (0.125 * (1.0 - D_START))));
    float m = START + STEP * (float)k;
    float dmm = ex - m;
    float s = cut * expf(-BETA * dmm * dmm) / nsq; // fold /nsq of diff into smear
    bx = s * d0; by = s * d1; bz = s * d2;
}

__global__ void k_main(const f32x4* __restrict__ W4,
                       const float* __restrict__ x,
                       float* __restrict__ part) {
    int a   = blockIdx.x >> 7;        // blockIdx / BPA
    int blk = blockIdx.x & (BPA - 1);

    __shared__ f32x4 p_lds[512];
    __shared__ float red[4][256];

    // ---- prologue: P for this block's 512 j-rows (j = blk*512 + r) ----
    {
        int t = threadIdx.x;
        int e = t >> 4, k = t & 15;
        int b = blk >> 3, dd = (blk & 7) * 2;
        f32x4 p0, p1;
        #pragma unroll
        for (int z = 0; z < 4; ++z) {
            float ux, uy, uz, v0x, v0y, v0z, v1x, v1y, v1z;
            pair_basis(x, z, a,      b, k, ux,  uy,  uz);
            pair_basis(x, z, dd,     e, k, v0x, v0y, v0z);
            pair_basis(x, z, dd + 1, e, k, v1x, v1y, v1z);
            p0[z] = ux * v0x + uy * v0y + uz * v0z;
            p1[z] = ux * v1x + uy * v1y + uz * v1z;
        }
        p_lds[t]       = p0;  // r = t       (d = dd)
        p_lds[t + 256] = p1;  // r = t + 256 (d = dd+1)
    }
    __syncthreads();

    int wave = threadIdx.x >> 6;
    int lane = threadIdx.x & 63;
    int og   = lane & 15;  // group of 4 'o' columns
    int rsub = lane >> 4;  // row within the 4-row group

    float acc[4][4] = {{0.f, 0.f, 0.f, 0.f}, {0.f, 0.f, 0.f, 0.f},
                       {0.f, 0.f, 0.f, 0.f}, {0.f, 0.f, 0.f, 0.f}};
    size_t rowbase = (size_t)a * NJ + (size_t)blk * 512;
    #pragma unroll 2
    for (int g = 0; g < 32; ++g) {
        int rloc = wave * 128 + g * 4 + rsub;   // 0..511
        f32x4 p4 = p_lds[rloc];                 // 64 B unique per wave-iter
        f32x4 w4 = __builtin_nontemporal_load(&W4[(rowbase + rloc) * 16 + og]);
        acc[0][0] += p4.x * w4.x; acc[0][1] += p4.x * w4.y; acc[0][2] += p4.x * w4.z; acc[0][3] += p4.x * w4.w;
        acc[1][0] += p4.y * w4.x; acc[1][1] += p4.y * w4.y; acc[1][2] += p4.y * w4.z; acc[1][3] += p4.y * w4.w;
        acc[2][0] += p4.z * w4.x; acc[2][1] += p4.z * w4.y; acc[2][2] += p4.z * w4.z; acc[2][3] += p4.z * w4.w;
        acc[3][0] += p4.w * w4.x; acc[3][1] += p4.w * w4.y; acc[3][2] += p4.w * w4.z; acc[3][3] += p4.w * w4.w;
    }
    // reduce across the 4 row-subgroups (lane bits 4,5)
    #pragma unroll
    for (int z = 0; z < 4; ++z) {
        #pragma unroll
        for (int c = 0; c < 4; ++c) {
            float v = acc[z][c];
            v += __shfl_xor(v, 16);
            v += __shfl_xor(v, 32);
            acc[z][c] = v;
        }
    }
    if (rsub == 0) {
        #pragma unroll
        for (int z = 0; z < 4; ++z) {
            #pragma unroll
            for (int c = 0; c < 4; ++c)
                red[wave][z * 64 + og * 4 + c] = acc[z][c];
        }
    }
    __syncthreads();
    int t = threadIdx.x; // (z*64 + o)
    float s = red[0][t] + red[1][t] + red[2][t] + red[3][t];
    part[((size_t)a * BPA + blk) * 256 + t] = s;
}

__global__ void k_out(const float* __restrict__ part, const float* __restrict__ w_fc,
                      const float* __restrict__ b_fc, float* __restrict__ out) {
    // one block per (z,a); 256 threads = 4 blk-quarters x 64 'o'
    int z = blockIdx.x >> 4, a = blockIdx.x & 15;
    int o = threadIdx.x & 63, bq = threadIdx.x >> 6;
    float s = 0.f;
    for (int blk = bq; blk < BPA; blk += 4)
        s += part[((size_t)a * BPA + blk) * 256 + z * 64 + o]; // coalesced over o
    __shared__ float red[4][64];
    red[bq][o] = s;
    __syncthreads();
    if (threadIdx.x < 64) {
        float h = red[0][o] + red[1][o] + red[2][o] + red[3][o];
        float v = h * (1.0f / (1.0f + expf(-h))) * w_fc[o]; // silu * weight
        #pragma unroll
        for (int off = 32; off >= 1; off >>= 1) v += __shfl_xor(v, off);
        if (o == 0) out[z * 16 + a] = v + b_fc[0];
    }
}

extern "C" void kernel_launch(void* const* d_in, const int* in_sizes, int n_in,
                              void* d_out, int out_size, void* d_ws, size_t ws_size,
                              hipStream_t stream) {
    const float* x    = (const float*)d_in[0];
    const float* W    = (const float*)d_in[1];
    const float* w_fc = (const float*)d_in[2];
    const float* b_fc = (const float*)d_in[3];
    float* ws = (float*)d_ws;

    float* part = ws;                 // 524,288 floats
    float* out  = (float*)d_out;

    k_main<<<16 * BPA, 256, 0, stream>>>((const f32x4*)W, x, part);
    k_out<<<64, 256, 0, stream>>>(part, w_fc, b_fc, out);
}

// Round 7
// 58.094 us; speedup vs baseline: 1.4652x; 1.0642x over previous
//
#include <hip/hip_runtime.h>
#include <math.h>

// Problem geometry (fixed): B=4, N=16, K=16, H=64, O=1
// W: (a,b,d,e,k,o) = 16^4 x 16 x 64 fp32 = 256 MiB -> memory-bound on W.
//
// h[z,a,o] = sum_{j=(b,d,e,k)} P[z,a,j] * W[a,j,o]
// P[z,a,j] = sum_c basis[z,a,b,k,c] * basis[z,d,e,k,c]
// out[z,a] = silu(h[z,a,:]) . w_fc + b_fc
//
// Neither basis nor P ever touch HBM: each k_main block covers 512
// consecutive j-rows (1 b, 2 d, 16 e, 16 k) and computes their P values
// straight from x (192 B, L1-hot) into 8 KB LDS in a ~500-cycle prologue.
//
// W loads are PLAIN (no nontemporal): W is exactly 256 MiB = Infinity Cache
// size; across graph replays L3 may retain much of it.
//
// ws layout (floats): part : [16][128][256] = 524,288 floats = 2 MB

#define NJ 65536
#define BPA 128  // blocks per 'a' -> 2048 blocks

typedef float f32x4 __attribute__((ext_vector_type(4)));

static constexpr double D_START = 0.006737946999085467; // exp(-5)

// basis vector (smear_k * diff / nsq) for pair (p,q) in batch z, rbf k
__device__ __forceinline__ void pair_basis(const float* __restrict__ x,
                                           int z, int p, int q, int k,
                                           float& bx, float& by, float& bz) {
    const float* xp = x + (z * 16 + p) * 3;
    const float* xq = x + (z * 16 + q) * 3;
    float d0 = xp[0] - xq[0], d1 = xp[1] - xq[1], d2 = xp[2] - xq[2];
    float nsq = d0 * d0 + d1 * d1 + d2 * d2 + 1e-5f;
    float nrm = sqrtf(nsq);
    float cut = (nrm < 5.0f) ? 0.5f * (cosf(nrm * 0.6283185307179586f) + 1.0f) : 0.0f;
    float ex = expf(-nrm); // alpha=1, CUT_LO=0
    const float START = (float)D_START;
    const float STEP  = (float)((1.0 - D_START) / 15.0);
    const float BETA  = (float)(1.0 / ((0.125 * (1.0 - D_START)) * (0.125 * (1.0 - D_START))));
    float m = START + STEP * (float)k;
    float dmm = ex - m;
    float s = cut * expf(-BETA * dmm * dmm) / nsq; // fold /nsq of diff into smear
    bx = s * d0; by = s * d1; bz = s * d2;
}

__global__ void k_main(const f32x4* __restrict__ W4,
                       const float* __restrict__ x,
                       float* __restrict__ part) {
    int a   = blockIdx.x >> 7;        // blockIdx / BPA
    int blk = blockIdx.x & (BPA - 1);

    __shared__ f32x4 p_lds[512];
    __shared__ float red[4][256];

    // ---- prologue: P for this block's 512 j-rows (j = blk*512 + r) ----
    {
        int t = threadIdx.x;
        int e = t >> 4, k = t & 15;
        int b = blk >> 3, dd = (blk & 7) * 2;
        f32x4 p0, p1;
        #pragma unroll
        for (int z = 0; z < 4; ++z) {
            float ux, uy, uz, v0x, v0y, v0z, v1x, v1y, v1z;
            pair_basis(x, z, a,      b, k, ux,  uy,  uz);
            pair_basis(x, z, dd,     e, k, v0x, v0y, v0z);
            pair_basis(x, z, dd + 1, e, k, v1x, v1y, v1z);
            p0[z] = ux * v0x + uy * v0y + uz * v0z;
            p1[z] = ux * v1x + uy * v1y + uz * v1z;
        }
        p_lds[t]       = p0;  // r = t       (d = dd)
        p_lds[t + 256] = p1;  // r = t + 256 (d = dd+1)
    }
    __syncthreads();

    int wave = threadIdx.x >> 6;
    int lane = threadIdx.x & 63;
    int og   = lane & 15;  // group of 4 'o' columns
    int rsub = lane >> 4;  // row within the 4-row group

    float acc[4][4] = {{0.f, 0.f, 0.f, 0.f}, {0.f, 0.f, 0.f, 0.f},
                       {0.f, 0.f, 0.f, 0.f}, {0.f, 0.f, 0.f, 0.f}};
    size_t rowbase = (size_t)a * NJ + (size_t)blk * 512;
    #pragma unroll 2
    for (int g = 0; g < 16; ++g) {
        int r0 = wave * 128 + g * 8 + rsub;     // rows r0 and r0+4
        f32x4 pA = p_lds[r0];
        f32x4 pB = p_lds[r0 + 4];
        f32x4 wA = W4[(rowbase + r0) * 16 + og];       // 1 KB contiguous per wave
        f32x4 wB = W4[(rowbase + r0 + 4) * 16 + og];   // next 1 KB
        acc[0][0] += pA.x * wA.x + pB.x * wB.x; acc[0][1] += pA.x * wA.y + pB.x * wB.y;
        acc[0][2] += pA.x * wA.z + pB.x * wB.z; acc[0][3] += pA.x * wA.w + pB.x * wB.w;
        acc[1][0] += pA.y * wA.x + pB.y * wB.x; acc[1][1] += pA.y * wA.y + pB.y * wB.y;
        acc[1][2] += pA.y * wA.z + pB.y * wB.z; acc[1][3] += pA.y * wA.w + pB.y * wB.w;
        acc[2][0] += pA.z * wA.x + pB.z * wB.x; acc[2][1] += pA.z * wA.y + pB.z * wB.y;
        acc[2][2] += pA.z * wA.z + pB.z * wB.z; acc[2][3] += pA.z * wA.w + pB.z * wB.w;
        acc[3][0] += pA.w * wA.x + pB.w * wB.x; acc[3][1] += pA.w * wA.y + pB.w * wB.y;
        acc[3][2] += pA.w * wA.z + pB.w * wB.z; acc[3][3] += pA.w * wA.w + pB.w * wB.w;
    }
    // reduce across the 4 row-subgroups (lane bits 4,5)
    #pragma unroll
    for (int z = 0; z < 4; ++z) {
        #pragma unroll
        for (int c = 0; c < 4; ++c) {
            float v = acc[z][c];
            v += __shfl_xor(v, 16);
            v += __shfl_xor(v, 32);
            acc[z][c] = v;
        }
    }
    if (rsub == 0) {
        #pragma unroll
        for (int z = 0; z < 4; ++z) {
            #pragma unroll
            for (int c = 0; c < 4; ++c)
                red[wave][z * 64 + og * 4 + c] = acc[z][c];
        }
    }
    __syncthreads();
    int t = threadIdx.x; // (z*64 + o)
    float s = red[0][t] + red[1][t] + red[2][t] + red[3][t];
    part[((size_t)a * BPA + blk) * 256 + t] = s;
}

__global__ void k_out(const float* __restrict__ part, const float* __restrict__ w_fc,
                      const float* __restrict__ b_fc, float* __restrict__ out) {
    // one block per (z,a); 256 threads = 4 blk-quarters x 64 'o'
    int z = blockIdx.x >> 4, a = blockIdx.x & 15;
    int o = threadIdx.x & 63, bq = threadIdx.x >> 6;
    float s = 0.f;
    for (int blk = bq; blk < BPA; blk += 4)
        s += part[((size_t)a * BPA + blk) * 256 + z * 64 + o]; // coalesced over o
    __shared__ float red[4][64];
    red[bq][o] = s;
    __syncthreads();
    if (threadIdx.x < 64) {
        float h = red[0][o] + red[1][o] + red[2][o] + red[3][o];
        float v = h * (1.0f / (1.0f + expf(-h))) * w_fc[o]; // silu * weight
        #pragma unroll
        for (int off = 32; off >= 1; off >>= 1) v += __shfl_xor(v, off);
        if (o == 0) out[z * 16 + a] = v + b_fc[0];
    }
}

extern "C" void kernel_launch(void* const* d_in, const int* in_sizes, int n_in,
                              void* d_out, int out_size, void* d_ws, size_t ws_size,
                              hipStream_t stream) {
    const float* x    = (const float*)d_in[0];
    const float* W    = (const float*)d_in[1];
    const float* w_fc = (const float*)d_in[2];
    const float* b_fc = (const float*)d_in[3];
    float* ws = (float*)d_ws;

    float* part = ws;                 // 524,288 floats
    float* out  = (float*)d_out;

    k_main<<<16 * BPA, 256, 0, stream>>>((const f32x4*)W, x, part);
    k_out<<<64, 256, 0, stream>>>(part, w_fc, b_fc, out);
}

// Round 8
// 46.828 us; speedup vs baseline: 1.8177x; 1.2406x over previous
//
#include <hip/hip_runtime.h>
#include <math.h>

// Problem geometry (fixed): B=4, N=16, K=16, H=64, O=1
// W: (a,b,d,e,k,o) = 16^4 x 16 x 64 fp32 = 256 MiB.
//
// h[z,a,o] = sum_{j=(b,d,e,k)} P[z,a,j] * W[a,j,o]
// P[z,a,j] = sum_c basis[z,a,b,k,c] * basis[z,d,e,k,c]
// out[z,a] = silu(h[z,a,:]) . w_fc + b_fc
//
// KEY: the cosine cutoff zeroes basis for pairs with dist >= 5; with
// x ~ N(0,3)^3 only ~29% of pairs are alive, so ~65% of W rows have
// P[z,row]==0 for ALL z and their loads are SKIPPED (bit-exact: those
// rows contribute 0*w). Skip granularity = 8 rows (one (d,e), uniform
// zero-ness) -> wave-uniform branch.
//
// Each block: 256 rows (1 b, 1 d, 16 e, 16 k). P computed from x straight
// into 4 KB LDS. Grid 4096 = 16 queued/CU for dynamic balancing.
//
// ws layout (floats): part : [16][256][256] = 1,048,576 floats = 4 MB

#define NJ 65536
#define BPA 256  // blocks per 'a' -> 4096 blocks

typedef float f32x4 __attribute__((ext_vector_type(4)));

static constexpr double D_START = 0.006737946999085467; // exp(-5)

// basis vector (smear_k * diff / nsq) for pair (p,q) in batch z, rbf k
__device__ __forceinline__ void pair_basis(const float* __restrict__ x,
                                           int z, int p, int q, int k,
                                           float& bx, float& by, float& bz) {
    const float* xp = x + (z * 16 + p) * 3;
    const float* xq = x + (z * 16 + q) * 3;
    float d0 = xp[0] - xq[0], d1 = xp[1] - xq[1], d2 = xp[2] - xq[2];
    float nsq = d0 * d0 + d1 * d1 + d2 * d2 + 1e-5f;
    float nrm = sqrtf(nsq);
    float cut = (nrm < 5.0f) ? 0.5f * (cosf(nrm * 0.6283185307179586f) + 1.0f) : 0.0f;
    float ex = expf(-nrm); // alpha=1, CUT_LO=0
    const float START = (float)D_START;
    const float STEP  = (float)((1.0 - D_START) / 15.0);
    const float BETA  = (float)(1.0 / ((0.125 * (1.0 - D_START)) * (0.125 * (1.0 - D_START))));
    float m = START + STEP * (float)k;
    float dmm = ex - m;
    float s = cut * expf(-BETA * dmm * dmm) / nsq; // fold /nsq of diff into smear
    bx = s * d0; by = s * d1; bz = s * d2;
}

__global__ void k_main(const f32x4* __restrict__ W4,
                       const float* __restrict__ x,
                       float* __restrict__ part) {
    int a   = blockIdx.x >> 8;        // blockIdx / BPA
    int blk = blockIdx.x & (BPA - 1); // (b,d)

    __shared__ f32x4 p_lds[256];
    __shared__ float red[4][256];

    // ---- prologue: P for this block's 256 j-rows (j = blk*256 + r) ----
    {
        int t = threadIdx.x;
        int e = t >> 4, k = t & 15;
        int b = blk >> 4, d = blk & 15;
        f32x4 p;
        #pragma unroll
        for (int z = 0; z < 4; ++z) {
            float ux, uy, uz, vx, vy, vz;
            pair_basis(x, z, a, b, k, ux, uy, uz);
            pair_basis(x, z, d, e, k, vx, vy, vz);
            p[z] = ux * vx + uy * vy + uz * vz;
        }
        p_lds[t] = p;
    }
    __syncthreads();

    int wave = threadIdx.x >> 6;
    int lane = threadIdx.x & 63;
    int og   = lane & 15;  // group of 4 'o' columns
    int rsub = lane >> 4;  // row within the 4-row group

    float acc[4][4] = {{0.f, 0.f, 0.f, 0.f}, {0.f, 0.f, 0.f, 0.f},
                       {0.f, 0.f, 0.f, 0.f}, {0.f, 0.f, 0.f, 0.f}};
    size_t rowbase = (size_t)a * NJ + (size_t)blk * 256;
    #pragma unroll 2
    for (int g = 0; g < 8; ++g) {
        int r0 = wave * 64 + g * 8 + rsub;      // rows r0 and r0+4, same (d,e)
        f32x4 pA = p_lds[r0];
        f32x4 pB = p_lds[r0 + 4];
        float mag = fabsf(pA.x) + fabsf(pA.y) + fabsf(pA.z) + fabsf(pA.w)
                  + fabsf(pB.x) + fabsf(pB.y) + fabsf(pB.z) + fabsf(pB.w);
        if (__any(mag != 0.0f)) {   // wave-uniform in practice; exact skip
            f32x4 wA = W4[(rowbase + r0) * 16 + og];       // 1 KB contiguous/wave
            f32x4 wB = W4[(rowbase + r0 + 4) * 16 + og];   // next 1 KB
            acc[0][0] += pA.x * wA.x + pB.x * wB.x; acc[0][1] += pA.x * wA.y + pB.x * wB.y;
            acc[0][2] += pA.x * wA.z + pB.x * wB.z; acc[0][3] += pA.x * wA.w + pB.x * wB.w;
            acc[1][0] += pA.y * wA.x + pB.y * wB.x; acc[1][1] += pA.y * wA.y + pB.y * wB.y;
            acc[1][2] += pA.y * wA.z + pB.y * wB.z; acc[1][3] += pA.y * wA.w + pB.y * wB.w;
            acc[2][0] += pA.z * wA.x + pB.z * wB.x; acc[2][1] += pA.z * wA.y + pB.z * wB.y;
            acc[2][2] += pA.z * wA.z + pB.z * wB.z; acc[2][3] += pA.z * wA.w + pB.z * wB.w;
            acc[3][0] += pA.w * wA.x + pB.w * wB.x; acc[3][1] += pA.w * wA.y + pB.w * wB.y;
            acc[3][2] += pA.w * wA.z + pB.w * wB.z; acc[3][3] += pA.w * wA.w + pB.w * wB.w;
        }
    }
    // reduce across the 4 row-subgroups (lane bits 4,5)
    #pragma unroll
    for (int z = 0; z < 4; ++z) {
        #pragma unroll
        for (int c = 0; c < 4; ++c) {
            float v = acc[z][c];
            v += __shfl_xor(v, 16);
            v += __shfl_xor(v, 32);
            acc[z][c] = v;
        }
    }
    if (rsub == 0) {
        #pragma unroll
        for (int z = 0; z < 4; ++z) {
            #pragma unroll
            for (int c = 0; c < 4; ++c)
                red[wave][z * 64 + og * 4 + c] = acc[z][c];
        }
    }
    __syncthreads();
    int t = threadIdx.x; // (z*64 + o)
    float s = red[0][t] + red[1][t] + red[2][t] + red[3][t];
    part[((size_t)a * BPA + blk) * 256 + t] = s;
}

__global__ void k_out(const float* __restrict__ part, const float* __restrict__ w_fc,
                      const float* __restrict__ b_fc, float* __restrict__ out) {
    // one block per (z,a); 256 threads = 4 blk-quarters x 64 'o'
    int z = blockIdx.x >> 4, a = blockIdx.x & 15;
    int o = threadIdx.x & 63, bq = threadIdx.x >> 6;
    float s = 0.f;
    for (int blk = bq; blk < BPA; blk += 4)
        s += part[((size_t)a * BPA + blk) * 256 + z * 64 + o]; // coalesced over o
    __shared__ float red[4][64];
    red[bq][o] = s;
    __syncthreads();
    if (threadIdx.x < 64) {
        float h = red[0][o] + red[1][o] + red[2][o] + red[3][o];
        float v = h * (1.0f / (1.0f + expf(-h))) * w_fc[o]; // silu * weight
        #pragma unroll
        for (int off = 32; off >= 1; off >>= 1) v += __shfl_xor(v, off);
        if (o == 0) out[z * 16 + a] = v + b_fc[0];
    }
}

extern "C" void kernel_launch(void* const* d_in, const int* in_sizes, int n_in,
                              void* d_out, int out_size, void* d_ws, size_t ws_size,
                              hipStream_t stream) {
    const float* x    = (const float*)d_in[0];
    const float* W    = (const float*)d_in[1];
    const float* w_fc = (const float*)d_in[2];
    const float* b_fc = (const float*)d_in[3];
    float* ws = (float*)d_ws;

    float* part = ws;                 // 1,048,576 floats
    float* out  = (float*)d_out;

    k_main<<<16 * BPA, 256, 0, stream>>>((const f32x4*)W, x, part);
    k_out<<<64, 256, 0, stream>>>(part, w_fc, b_fc, out);
}

// Round 9
// 29.338 us; speedup vs baseline: 2.9013x; 1.5962x over previous
//
#include <hip/hip_runtime.h>
#include <math.h>

// Problem geometry (fixed): B=4, N=16, K=16, H=64, O=1
// W: (a,b,d,e,k,o) = 16^4 x 16 x 64 fp32 = 256 MiB.
//
// h[z,a,o] = sum_{j=(b,d,e,k)} P[z,a,j] * W[a,j,o]
// P[z,a,j] = sum_c basis[z,a,b,k,c] * basis[z,d,e,k,c]
// out[z,a] = silu(h[z,a,:]) . w_fc + b_fc
//
// Cosine cutoff (dist>=5) + diff==0 diagonal kill most P exactly: only
// ~26% of W rows have any nonzero P -> skip their loads (bit-exact).
// Aliveness is computed IN-REGISTER before the LDS write and turned into
// a per-wave 16-bit group mask via __ballot -> the main loop visits only
// alive 8-row groups and never branches on an LDS load.
//
// Block = 512 rows (1 b, 2 d, 16 e, 16 k); grid 2048 (8 blocks/CU).
// ws layout (floats): part : [16][128][256] = 524,288 floats = 2 MB

#define NJ 65536
#define BPA 128  // blocks per 'a' -> 2048 blocks

typedef float f32x4 __attribute__((ext_vector_type(4)));

static constexpr double D_START = 0.006737946999085467; // exp(-5)

// basis vector (smear_k * diff / nsq) for pair (p,q) in batch z, rbf k.
// Returns false (and garbage b*) when the cutoff kills the pair.
__device__ __forceinline__ bool pair_basis(const float* __restrict__ x,
                                           int z, int p, int q, int k,
                                           float& bx, float& by, float& bz) {
    const float* xp = x + (z * 16 + p) * 3;
    const float* xq = x + (z * 16 + q) * 3;
    float d0 = xp[0] - xq[0], d1 = xp[1] - xq[1], d2 = xp[2] - xq[2];
    float nsq = d0 * d0 + d1 * d1 + d2 * d2 + 1e-5f;
    float nrm = sqrtf(nsq);
    if (nrm >= 5.0f) return false;                 // cut == 0 -> basis == 0
    float cut = 0.5f * (cosf(nrm * 0.6283185307179586f) + 1.0f);
    float ex = expf(-nrm); // alpha=1, CUT_LO=0
    const float START = (float)D_START;
    const float STEP  = (float)((1.0 - D_START) / 15.0);
    const float BETA  = (float)(1.0 / ((0.125 * (1.0 - D_START)) * (0.125 * (1.0 - D_START))));
    float m = START + STEP * (float)k;
    float dmm = ex - m;
    float s = cut * expf(-BETA * dmm * dmm) / nsq; // fold /nsq of diff into smear
    bx = s * d0; by = s * d1; bz = s * d2;
    return true;
}

__global__ __launch_bounds__(256) void k_main(const f32x4* __restrict__ W4,
                                              const float* __restrict__ x,
                                              float* __restrict__ part) {
    int a   = blockIdx.x >> 7;        // blockIdx / BPA
    int blk = blockIdx.x & (BPA - 1); // (b, d-pair)

    __shared__ f32x4 p_lds[512];
    __shared__ float red[4][256];

    // ---- prologue: P for this block's 512 j-rows (j = blk*512 + rloc) ----
    // thread t covers rows t (d=dd) and t+256 (d=dd+1)
    int t = threadIdx.x;
    f32x4 p0 = {0.f, 0.f, 0.f, 0.f}, p1 = {0.f, 0.f, 0.f, 0.f};
    {
        int e = t >> 4, k = t & 15;
        int b = blk >> 3, dd = (blk & 7) * 2;
        #pragma unroll
        for (int z = 0; z < 4; ++z) {
            float ux, uy, uz;
            if (pair_basis(x, z, a, b, k, ux, uy, uz)) { // block-uniform branch
                float vx, vy, vz;
                if (pair_basis(x, z, dd, e, k, vx, vy, vz))
                    p0[z] = ux * vx + uy * vy + uz * vz;
                if (pair_basis(x, z, dd + 1, e, k, vx, vy, vz))
                    p1[z] = ux * vx + uy * vy + uz * vz;
            }
        }
    }
    bool f0 = (fabsf(p0.x) + fabsf(p0.y) + fabsf(p0.z) + fabsf(p0.w)) != 0.0f;
    bool f1 = (fabsf(p1.x) + fabsf(p1.y) + fabsf(p1.z) + fabsf(p1.w)) != 0.0f;
    unsigned long long bal0 = __ballot(f0);  // rows [w*64, w*64+64)
    unsigned long long bal1 = __ballot(f1);  // rows [256+w*64, ...)
    p_lds[t]       = p0;
    p_lds[t + 256] = p1;
    __syncthreads();

    int wave = threadIdx.x >> 6;
    int lane = threadIdx.x & 63;
    int og   = lane & 15;  // group of 4 'o' columns
    int rsub = lane >> 4;  // row within the 4-row group

    // group mask: bits 0..7 = A-half groups, 8..15 = B-half groups
    unsigned mask = 0;
    #pragma unroll
    for (int g = 0; g < 8; ++g) {
        if ((bal0 >> (8 * g)) & 0xFFull) mask |= 1u << g;
        if ((bal1 >> (8 * g)) & 0xFFull) mask |= 1u << (g + 8);
    }

    float acc[4][4] = {{0.f, 0.f, 0.f, 0.f}, {0.f, 0.f, 0.f, 0.f},
                       {0.f, 0.f, 0.f, 0.f}, {0.f, 0.f, 0.f, 0.f}};
    size_t rowbase = (size_t)a * NJ + (size_t)blk * 512;
    while (mask) {  // wave-uniform: mask derived from ballots
        int g = __builtin_ctz(mask);
        mask &= mask - 1;
        int rloc = ((g & 8) ? 256 : 0) + wave * 64 + (g & 7) * 8 + rsub;
        f32x4 pA = p_lds[rloc];
        f32x4 pB = p_lds[rloc + 4];
        f32x4 wA = W4[(rowbase + rloc) * 16 + og];       // 1 KB contiguous/wave
        f32x4 wB = W4[(rowbase + rloc + 4) * 16 + og];   // 1 KB contiguous/wave
        acc[0][0] += pA.x * wA.x + pB.x * wB.x; acc[0][1] += pA.x * wA.y + pB.x * wB.y;
        acc[0][2] += pA.x * wA.z + pB.x * wB.z; acc[0][3] += pA.x * wA.w + pB.x * wB.w;
        acc[1][0] += pA.y * wA.x + pB.y * wB.x; acc[1][1] += pA.y * wA.y + pB.y * wB.y;
        acc[1][2] += pA.y * wA.z + pB.y * wB.z; acc[1][3] += pA.y * wA.w + pB.y * wB.w;
        acc[2][0] += pA.z * wA.x + pB.z * wB.x; acc[2][1] += pA.z * wA.y + pB.z * wB.y;
        acc[2][2] += pA.z * wA.z + pB.z * wB.z; acc[2][3] += pA.z * wA.w + pB.z * wB.w;
        acc[3][0] += pA.w * wA.x + pB.w * wB.x; acc[3][1] += pA.w * wA.y + pB.w * wB.y;
        acc[3][2] += pA.w * wA.z + pB.w * wB.z; acc[3][3] += pA.w * wA.w + pB.w * wB.w;
    }
    // reduce across the 4 row-subgroups (lane bits 4,5)
    #pragma unroll
    for (int z = 0; z < 4; ++z) {
        #pragma unroll
        for (int c = 0; c < 4; ++c) {
            float v = acc[z][c];
            v += __shfl_xor(v, 16);
            v += __shfl_xor(v, 32);
            acc[z][c] = v;
        }
    }
    if (rsub == 0) {
        #pragma unroll
        for (int z = 0; z < 4; ++z) {
            #pragma unroll
            for (int c = 0; c < 4; ++c)
                red[wave][z * 64 + og * 4 + c] = acc[z][c];
        }
    }
    __syncthreads();
    // (z*64 + o) = t
    float s = red[0][t] + red[1][t] + red[2][t] + red[3][t];
    part[((size_t)a * BPA + blk) * 256 + t] = s;
}

__global__ void k_out(const float* __restrict__ part, const float* __restrict__ w_fc,
                      const float* __restrict__ b_fc, float* __restrict__ out) {
    // one block per (z,a); 256 threads = 4 blk-quarters x 64 'o'
    int z = blockIdx.x >> 4, a = blockIdx.x & 15;
    int o = threadIdx.x & 63, bq = threadIdx.x >> 6;
    float s = 0.f;
    for (int blk = bq; blk < BPA; blk += 4)
        s += part[((size_t)a * BPA + blk) * 256 + z * 64 + o]; // coalesced over o
    __shared__ float red[4][64];
    red[bq][o] = s;
    __syncthreads();
    if (threadIdx.x < 64) {
        float h = red[0][o] + red[1][o] + red[2][o] + red[3][o];
        float v = h * (1.0f / (1.0f + expf(-h))) * w_fc[o]; // silu * weight
        #pragma unroll
        for (int off = 32; off >= 1; off >>= 1) v += __shfl_xor(v, off);
        if (o == 0) out[z * 16 + a] = v + b_fc[0];
    }
}

extern "C" void kernel_launch(void* const* d_in, const int* in_sizes, int n_in,
                              void* d_out, int out_size, void* d_ws, size_t ws_size,
                              hipStream_t stream) {
    const float* x    = (const float*)d_in[0];
    const float* W    = (const float*)d_in[1];
    const float* w_fc = (const float*)d_in[2];
    const float* b_fc = (const float*)d_in[3];
    float* ws = (float*)d_ws;

    float* part = ws;                 // 524,288 floats
    float* out  = (float*)d_out;

    k_main<<<16 * BPA, 256, 0, stream>>>((const f32x4*)W, x, part);
    k_out<<<64, 256, 0, stream>>>(part, w_fc, b_fc, out);
}